// Round 1
// baseline (395.489 us; speedup 1.0000x reference)
//
#include <hip/hip_runtime.h>
#include <math.h>

#define EMB   4096
#define DIM   4096
#define TPREV 8192
#define TTOT  8193   // TPREV + 1 (appended current step)

// ws layout (floats): [0,4096)=q  [4096,8192)=k  [8192,12288)=v  [12288,12288+8193)=scores/a

// ---------------------------------------------------------------------------
// K1: q,k,v GEMVs (wave-per-row, float4 coalesced) + zero the score buffer.
// grid 3072 x 256: 12288 waves -> 3 matrices x 4096 rows.
__global__ __launch_bounds__(256) void qkv_kernel(
    const float* __restrict__ x,
    const float* __restrict__ Wq, const float* __restrict__ Wk,
    const float* __restrict__ Wv, float* __restrict__ ws) {
    // zero scores region (blocks 0..32 cover 8448 >= 8193 elements)
    float* scores = ws + 3 * DIM;
    int gtid = blockIdx.x * 256 + threadIdx.x;
    if (gtid < TTOT) scores[gtid] = 0.0f;

    int wave = threadIdx.x >> 6;
    int lane = threadIdx.x & 63;
    int g = blockIdx.x * 4 + wave;      // global wave id, 0..12287
    int m = g >> 12;                    // which matrix (0..2)
    int r = g & 4095;                   // row
    const float* W = (m == 0) ? Wq : (m == 1) ? Wk : Wv;

    const float4* row = (const float4*)(W + (size_t)r * EMB);
    const float4* xv  = (const float4*)x;

    float acc = 0.0f;
#pragma unroll
    for (int i = 0; i < EMB / 256; ++i) {       // 16 iterations
        float4 a = row[i * 64 + lane];
        float4 b = xv[i * 64 + lane];
        acc += a.x * b.x + a.y * b.y + a.z * b.z + a.w * b.w;
    }
#pragma unroll
    for (int off = 32; off > 0; off >>= 1) acc += __shfl_down(acc, off, 64);
    if (lane == 0) ws[m * DIM + r] = acc;
}

// ---------------------------------------------------------------------------
// K2: score partials. grid (9, 64):
//   blockIdx.x = t-tile (1024 wide; tile 8 covers only the appended t=8192)
//   blockIdx.y = d-chunk (64 rows of K_cache)
// Each thread owns 4 consecutive t (float4 load, coalesced 1KB/wave/row),
// accumulates over 64 d, then one atomicAdd per t into scores.
__global__ __launch_bounds__(256) void score_kernel(
    const float* __restrict__ Kc, float* __restrict__ ws) {
    const float* q    = ws;
    const float* kvec = ws + DIM;
    float* scores     = ws + 3 * DIM;

    __shared__ float qs[64];
    int d0 = blockIdx.y * 64;
    if (threadIdx.x < 64) qs[threadIdx.x] = q[d0 + threadIdx.x];
    __syncthreads();

    int t = blockIdx.x * 1024 + threadIdx.x * 4;
    if (t + 3 < TPREV) {
        float4 acc = {0.f, 0.f, 0.f, 0.f};
#pragma unroll 8
        for (int i = 0; i < 64; ++i) {
            const float4 kv = *(const float4*)(Kc + (size_t)(d0 + i) * TPREV + t);
            float qd = qs[i];
            acc.x += qd * kv.x;
            acc.y += qd * kv.y;
            acc.z += qd * kv.z;
            acc.w += qd * kv.w;
        }
        atomicAdd(&scores[t + 0], acc.x);
        atomicAdd(&scores[t + 1], acc.y);
        atomicAdd(&scores[t + 2], acc.z);
        atomicAdd(&scores[t + 3], acc.w);
    } else if (t == TPREV) {
        // appended column: K[:, 8192] = k
        float s = 0.0f;
#pragma unroll 8
        for (int i = 0; i < 64; ++i) s += qs[i] * kvec[d0 + i];
        atomicAdd(&scores[TPREV], s);
    }
}

// ---------------------------------------------------------------------------
// K3: a = sigmoid(scores / sqrt(4096)), in place.
__global__ void sigmoid_kernel(float* __restrict__ ws) {
    float* scores = ws + 3 * DIM;
    int i = blockIdx.x * 256 + threadIdx.x;
    if (i < TTOT) {
        float s = scores[i] * 0.015625f;   // 1/sqrt(4096) = 1/64
        scores[i] = 1.0f / (1.0f + __expf(-s));
    }
}

// ---------------------------------------------------------------------------
// K4: z[d] = dot(V_cache[d,:], a[0:8192]) + v[d] * a[8192]
// wave-per-row; a (32KB) is L2/L3 resident broadcast.
__global__ __launch_bounds__(256) void out_kernel(
    const float* __restrict__ Vc, const float* __restrict__ ws,
    float* __restrict__ out) {
    const float* vvec = ws + 2 * DIM;
    const float* a    = ws + 3 * DIM;

    int wave = threadIdx.x >> 6;
    int lane = threadIdx.x & 63;
    int d = blockIdx.x * 4 + wave;

    const float4* row = (const float4*)(Vc + (size_t)d * TPREV);
    const float4* av  = (const float4*)a;

    float acc = 0.0f;
#pragma unroll 4
    for (int i = 0; i < TPREV / 256; ++i) {     // 32 iterations
        float4 vv = row[i * 64 + lane];
        float4 aa = av[i * 64 + lane];
        acc += vv.x * aa.x + vv.y * aa.y + vv.z * aa.z + vv.w * aa.w;
    }
#pragma unroll
    for (int off = 32; off > 0; off >>= 1) acc += __shfl_down(acc, off, 64);
    if (lane == 0) out[d] = acc + vvec[d] * a[TPREV];
}

// ---------------------------------------------------------------------------
extern "C" void kernel_launch(void* const* d_in, const int* in_sizes, int n_in,
                              void* d_out, int out_size, void* d_ws, size_t ws_size,
                              hipStream_t stream) {
    const float* x  = (const float*)d_in[0];
    const float* Wq = (const float*)d_in[1];
    const float* Wk = (const float*)d_in[2];
    const float* Wv = (const float*)d_in[3];
    const float* Kc = (const float*)d_in[4];
    const float* Vc = (const float*)d_in[5];
    float* out = (float*)d_out;
    float* ws  = (float*)d_ws;

    qkv_kernel<<<3072, 256, 0, stream>>>(x, Wq, Wk, Wv, ws);
    score_kernel<<<dim3(9, 64), 256, 0, stream>>>(Kc, ws);
    sigmoid_kernel<<<33, 256, 0, stream>>>(ws);
    out_kernel<<<1024, 256, 0, stream>>>(Vc, ws, out);
}